// Round 9
// baseline (4085.125 us; speedup 1.0000x reference)
//
#include <hip/hip_runtime.h>
#include <stdint.h>

#define SLEN 100
#define NSEQ 4096
#define PRED 12

typedef unsigned short ushort_t;
typedef unsigned int uint_t;

#if __has_builtin(__builtin_amdgcn_rcpf)
#define RCP(x) __builtin_amdgcn_rcpf(x)
#else
#define RCP(x) (1.0f/(x))
#endif

__device__ __forceinline__ float bfu(ushort_t u){ return __uint_as_float(((uint_t)u)<<16); }
__device__ __forceinline__ float bflo(uint_t u){ return __uint_as_float(u<<16); }
__device__ __forceinline__ float bfhi(uint_t u){ return __uint_as_float(u & 0xffff0000u); }
__device__ __forceinline__ ushort_t f2bf(float f){
  uint_t u = __float_as_uint(f);
  u += 0x7fffu + ((u>>16)&1u);
  return (ushort_t)(u>>16);
}
__device__ __forceinline__ uint_t pk2(float a, float b){
  return (uint_t)f2bf(a) | ((uint_t)f2bf(b)<<16);
}
__device__ __forceinline__ float fsig(float x){ return RCP(1.f + __expf(-x)); }
__device__ __forceinline__ float ftanh(float x){ float e = __expf(x+x); return 1.f - 2.f*RCP(e+1.f); }
// force v_readlane (uniform broadcast on the VALU pipe, NOT ds_bpermute)
__device__ __forceinline__ float RL(float v, int k){
  return __uint_as_float((uint_t)__builtin_amdgcn_readlane((int)__float_as_uint(v), k));
}

// ---------------- Encoder: bidirectional GRU, ZERO LDS ----------------
// grid 512: blockIdx<256 fwd, >=256 bwd. block=256 (4 waves), wave = 4 seqs.
// Lane j holds Whh row j in 96 packed-bf16 VGPRs; h broadcast by readlane.
// Inner loop: 19 VALU / k, no LDS instructions -> pure VALU-issue bound.
__global__ __launch_bounds__(256, 2)
void k_encoder(const float* __restrict__ src,
               const float* __restrict__ WihF, const float* __restrict__ WhhF,
               const float* __restrict__ bihF, const float* __restrict__ bhhF,
               const float* __restrict__ WihB, const float* __restrict__ WhhB,
               const float* __restrict__ bihB, const float* __restrict__ bhhB,
               ushort_t* __restrict__ encO, float* __restrict__ hlast)
{
  const int t = threadIdx.x;
  const int dir = blockIdx.x >> 8;
  const int grp = blockIdx.x & 255;
  const float* Wih = dir ? WihB : WihF;
  const float* Whh = dir ? WhhB : WhhF;
  const float* bih = dir ? bihB : bihF;
  const float* bhh = dir ? bhhB : bhhF;

  const int w = t >> 6, lane = t & 63;
  const int n0 = grp*16 + w*4;

  // lane j's weight rows, packed bf16 (96 VGPRs)
  uint_t wrz[64], wn2[32];
  #pragma unroll
  for (int k = 0; k < 64; ++k)
    wrz[k] = pk2(Whh[lane*64 + k], Whh[(64+lane)*64 + k]);
  #pragma unroll
  for (int kk = 0; kk < 32; ++kk)
    wn2[kk] = pk2(Whh[(128+lane)*64 + 2*kk], Whh[(128+lane)*64 + 2*kk+1]);

  float rw[3][3];
  #pragma unroll
  for (int g = 0; g < 3; ++g)
    #pragma unroll
    for (int i = 0; i < 3; ++i)
      rw[g][i] = Wih[(g*64 + lane)*3 + i];
  const float br  = bih[lane]     + bhh[lane];
  const float bz  = bih[64+lane]  + bhh[64+lane];
  const float bni = bih[128+lane];
  const float bnh = bhh[128+lane];

  float h0=0.f, h1=0.f, h2=0.f, h3=0.f;

  // prefetch step-0 x (12 values: 4 seqs x 3 features on lanes 0..11)
  float xv = 0.f;
  {
    const int s0 = dir ? (SLEN-1) : 0;
    if (lane < 12) {
      int q = lane/3, i = lane - q*3, n = n0 + q;
      xv = src[(((n>>5)*SLEN + s0)*96) + (n&31)*3 + i];
    }
  }

  for (int st = 0; st < SLEN; ++st) {
    const int sidx = dir ? (SLEN-1 - st) : st;
    // broadcast current x from lanes 0..11
    const float x00=RL(xv,0),  x01=RL(xv,1),  x02=RL(xv,2);
    const float x10=RL(xv,3),  x11=RL(xv,4),  x12=RL(xv,5);
    const float x20=RL(xv,6),  x21=RL(xv,7),  x22=RL(xv,8);
    const float x30=RL(xv,9),  x31=RL(xv,10), x32=RL(xv,11);
    // issue next step's load; latency hides under the k-loop
    float xnx = 0.f;
    if (st+1 < SLEN) {
      const int sn = dir ? (SLEN-2 - st) : (st+1);
      if (lane < 12) {
        int q = lane/3, i = lane - q*3, n = n0 + q;
        xnx = src[(((n>>5)*SLEN + sn)*96) + (n&31)*3 + i];
      }
    }

    float ar0 = br  + x00*rw[0][0] + x01*rw[0][1] + x02*rw[0][2];
    float az0 = bz  + x00*rw[1][0] + x01*rw[1][1] + x02*rw[1][2];
    float gn0 = bni + x00*rw[2][0] + x01*rw[2][1] + x02*rw[2][2];
    float ar1 = br  + x10*rw[0][0] + x11*rw[0][1] + x12*rw[0][2];
    float az1 = bz  + x10*rw[1][0] + x11*rw[1][1] + x12*rw[1][2];
    float gn1 = bni + x10*rw[2][0] + x11*rw[2][1] + x12*rw[2][2];
    float ar2 = br  + x20*rw[0][0] + x21*rw[0][1] + x22*rw[0][2];
    float az2 = bz  + x20*rw[1][0] + x21*rw[1][1] + x22*rw[1][2];
    float gn2 = bni + x20*rw[2][0] + x21*rw[2][1] + x22*rw[2][2];
    float ar3 = br  + x30*rw[0][0] + x31*rw[0][1] + x32*rw[0][2];
    float az3 = bz  + x30*rw[1][0] + x31*rw[1][1] + x32*rw[1][2];
    float gn3 = bni + x30*rw[2][0] + x31*rw[2][1] + x32*rw[2][2];
    float an0 = bnh, an1 = bnh, an2 = bnh, an3 = bnh;

    #pragma unroll
    for (int k = 0; k < 64; ++k) {
      const float hk0 = RL(h0,k), hk1 = RL(h1,k), hk2 = RL(h2,k), hk3 = RL(h3,k);
      const float wr_ = bflo(wrz[k]), wz_ = bfhi(wrz[k]);
      const float wn_ = (k & 1) ? bfhi(wn2[k>>1]) : bflo(wn2[k>>1]);
      ar0 += hk0*wr_; az0 += hk0*wz_; an0 += hk0*wn_;
      ar1 += hk1*wr_; az1 += hk1*wz_; an1 += hk1*wn_;
      ar2 += hk2*wr_; az2 += hk2*wz_; an2 += hk2*wn_;
      ar3 += hk3*wr_; az3 += hk3*wz_; an3 += hk3*wn_;
    }
    {
      float r = fsig(ar0), z = fsig(az0);
      float nn = ftanh(gn0 + r*an0);
      h0 = nn + z*(h0 - nn);
      encO[((n0+0)*SLEN + sidx)*128 + dir*64 + lane] = f2bf(h0);
    }
    {
      float r = fsig(ar1), z = fsig(az1);
      float nn = ftanh(gn1 + r*an1);
      h1 = nn + z*(h1 - nn);
      encO[((n0+1)*SLEN + sidx)*128 + dir*64 + lane] = f2bf(h1);
    }
    {
      float r = fsig(ar2), z = fsig(az2);
      float nn = ftanh(gn2 + r*an2);
      h2 = nn + z*(h2 - nn);
      encO[((n0+2)*SLEN + sidx)*128 + dir*64 + lane] = f2bf(h2);
    }
    {
      float r = fsig(ar3), z = fsig(az3);
      float nn = ftanh(gn3 + r*an3);
      h3 = nn + z*(h3 - nn);
      encO[((n0+3)*SLEN + sidx)*128 + dir*64 + lane] = f2bf(h3);
    }
    xv = xnx;
  }
  hlast[(dir*NSEQ + n0+0)*64 + lane] = h0;
  hlast[(dir*NSEQ + n0+1)*64 + lane] = h1;
  hlast[(dir*NSEQ + n0+2)*64 + lane] = h2;
  hlast[(dir*NSEQ + n0+3)*64 + lane] = h3;
}

// ---------------- h_dec0 = [hf|hb] @ e2d_W.T + e2d_b ----------------
__global__ __launch_bounds__(256)
void k_hdec0(const float* __restrict__ hlast, const float* __restrict__ e2dW,
             const float* __restrict__ e2db, float* __restrict__ h0g)
{
  const int t = threadIdx.x, w = t>>6, lane = t&63;
  const int n = blockIdx.x*4 + w;
  const float* hf = hlast + n*64;
  const float* hb = hlast + (NSEQ + n)*64;
  float a0 = e2db[lane], a1 = 0.f;
  #pragma unroll 4
  for (int k = 0; k < 64; k += 2) {
    a0 += hf[k]  *e2dW[lane*128 + k]      + hb[k]  *e2dW[lane*128 + 64 + k];
    a1 += hf[k+1]*e2dW[lane*128 + k + 1]  + hb[k+1]*e2dW[lane*128 + 65 + k];
  }
  h0g[n*64 + lane] = a0 + a1;
}

// ---------------- encWb = enc_out @ We.T + attn_b (step-invariant) ----------------
__global__ __launch_bounds__(512)
void k_encwb(const ushort_t* __restrict__ encO, const float* __restrict__ attnW,
             const float* __restrict__ attnb, ushort_t* __restrict__ encWbG)
{
  __shared__ __align__(16) uint_t encL[96*64];   // 96 rows x 128 bf16
  __shared__ __align__(16) float  WeT[128*64];   // [k][j]
  const int t = threadIdx.x;
  const int row0 = blockIdx.x * 96;
  const int nrows = (409600 - row0) < 96 ? (409600 - row0) : 96;
  const uint_t* srcp = (const uint_t*)(encO) + row0*64;
  for (int e = t; e < nrows*64; e += 512) encL[e] = srcp[e];
  for (int e = t; e < 8192; e += 512) {
    int j = e >> 7, k = e & 127;
    WeT[k*64 + j] = attnW[j*192 + 64 + k];
  }
  __syncthreads();
  const int w = t>>6, lane = t&63;
  const float ab = attnb[lane];
  for (int rr = 0; rr < 12; ++rr) {
    int row = w*12 + rr;
    if (row0 + row >= 409600) break;
    float a0 = ab, a1 = 0.f;
    #pragma unroll 8
    for (int k2 = 0; k2 < 64; ++k2) {
      uint_t u = encL[row*64 + k2];
      a0 += bflo(u)*WeT[(2*k2  )*64 + lane];
      a1 += bfhi(u)*WeT[(2*k2+1)*64 + lane];
    }
    encWbG[(row0+row)*64 + lane] = f2bf(a0 + a1);
  }
}

// ---------------- Decoder: 12 fused steps, 4 barriers/step ----------------
// block = 1 seq, 256 thr. hW redundantly per-wave into wave-private LDS slice;
// ah kept in the consuming thread's register; softmax redundantly per-wave
// (waves 0,1) fused with the ctx loop. LDS 43KB -> 3 blocks/CU.
__global__ __launch_bounds__(256, 3)
void k_decoder(const float* __restrict__ src,
               const ushort_t* __restrict__ encO, const ushort_t* __restrict__ encWbG,
               const float* __restrict__ h0g,
               const float* __restrict__ attnW, const float* __restrict__ attnv,
               const float* __restrict__ dWih, const float* __restrict__ dWhh,
               const float* __restrict__ dbih, const float* __restrict__ dbhh,
               const float* __restrict__ outWg, const float* __restrict__ outbg,
               float* __restrict__ out)
{
  __shared__ __align__(16) ushort_t encBT[128*102]; // enc^T [k][s], pad 102 (odd dwords)
  __shared__ __align__(16) ushort_t encWbL[100*66]; // [s][j], pad 66
  __shared__ __align__(16) float hWw[4][64];        // per-wave hW slices
  __shared__ __align__(16) float scoreW[2][104];    // per-wave score slices (waves 0,1)
  __shared__ __align__(16) float ctx[128];
  __shared__ __align__(16) float gbuf[256];
  __shared__ __align__(16) float hbuf[64];
  __shared__ __align__(16) float vat[64];
  __shared__ __align__(16) float outWs[192];
  __shared__ __align__(16) float outbs[4];
  __shared__ __align__(16) float inpb[4];

  const int t = threadIdx.x;
  const int n = blockIdx.x;
  const int w = t >> 6, lane = t & 63;

  // Register weights:
  uint_t wihc[64];  // t<192: dWih ctx-part row t, packed bf16
  uint_t whh2[32];  // t<192: dWhh row t, packed bf16
  uint_t whp[32];   // all:   attnW hid-part row j=lane, packed bf16
  float  wx0=0.f, wx1=0.f, wx2=0.f;  // t<192: dWih x-part (fp32)
  float  brz_r=0.f, bni_r=0.f, bnh_r=0.f;
  #pragma unroll
  for (int kk = 0; kk < 32; ++kk)
    whp[kk] = pk2(attnW[lane*192 + 2*kk], attnW[lane*192 + 2*kk + 1]);
  if (t < 192) {
    const float* wr = dWih + t*131 + 3;
    #pragma unroll
    for (int kk = 0; kk < 64; ++kk) wihc[kk] = pk2(wr[2*kk], wr[2*kk+1]);
    const float* hr = dWhh + t*64;
    #pragma unroll
    for (int kk = 0; kk < 32; ++kk) whh2[kk] = pk2(hr[2*kk], hr[2*kk+1]);
    wx0 = dWih[t*131 + 0]; wx1 = dWih[t*131 + 1]; wx2 = dWih[t*131 + 2];
    if (t < 128) brz_r = dbih[t] + dbhh[t];
    else { bni_r = dbih[t]; bnh_r = dbhh[t]; }   // t in [128,192): rows 128..191 = n-gate
  }
  // LDS fills
  const ushort_t* eb = encO + n*12800;
  for (int e = t; e < 12800; e += 256) {
    int s = e >> 7, k = e & 127;
    encBT[k*102 + s] = eb[e];
  }
  const ushort_t* ew = encWbG + n*6400;
  for (int e = t; e < 6400; e += 256) {
    int s = e >> 6, j = e & 63;
    encWbL[s*66 + j] = ew[e];
  }
  if (t < 192) outWs[t] = outWg[t];
  if (t < 64) { vat[t] = attnv[t]; hbuf[t] = h0g[n*64+t]; }
  if (t < 4)  outbs[t] = (t < 3) ? outbg[t] : 0.f;
  if (t < 3)  inpb[t] = src[((n>>5)*SLEN + (SLEN-1))*96 + (n&31)*3 + t];
  __syncthreads();

  for (int st = 0; st < PRED; ++st) {
    // --- pre-B (no barrier): per-wave redundant hW; per-thread ah ---
    {
      float hw = 0.f;
      #pragma unroll
      for (int kk = 0; kk < 32; ++kk) {
        float2 h2 = *(const float2*)&hbuf[2*kk];   // broadcast
        uint_t u = whp[kk];
        hw += h2.x*bflo(u) + h2.y*bfhi(u);
      }
      hWw[w][lane] = hw;   // wave-private
    }
    float ah = 0.f;
    if (t < 192) {
      #pragma unroll
      for (int kk = 0; kk < 32; ++kk) {
        float2 h2 = *(const float2*)&hbuf[2*kk];   // broadcast
        uint_t u = whh2[kk];
        ah += h2.x*bflo(u) + h2.y*bfhi(u);
      }
    }
    __builtin_amdgcn_wave_barrier();
    // --- B: score partials, (jh = t>>7, s = t&127); reads own wave's hW slice ---
    {
      const int s = t & 127, jh = t >> 7;
      if (s < 100) {
        const ushort_t* erow = &encWbL[s*66 + jh*32];
        float p = 0.f;
        #pragma unroll
        for (int j4 = 0; j4 < 8; ++j4) {
          float4 hw4 = *(const float4*)&hWw[w][jh*32 + j4*4];
          uint_t u0 = *(const uint_t*)&erow[j4*4];
          uint_t u1 = *(const uint_t*)&erow[j4*4 + 2];
          float4 vv = *(const float4*)&vat[jh*32 + j4*4];
          p += ftanh(hw4.x + bflo(u0))*vv.x;
          p += ftanh(hw4.y + bfhi(u0))*vv.y;
          p += ftanh(hw4.z + bflo(u1))*vv.z;
          p += ftanh(hw4.w + bfhi(u1))*vv.w;
        }
        gbuf[t] = p;
      }
    }
    __syncthreads();                                   // barrier 1
    // --- C+D fused: waves 0,1 redundant softmax -> own slice -> ctx ---
    if (t < 128) {
      float sA = gbuf[lane] + gbuf[128+lane];
      float sB = (lane < 36) ? (gbuf[64+lane] + gbuf[192+lane]) : -1e30f;
      float m = fmaxf(sA, sB);
      #pragma unroll
      for (int o = 32; o > 0; o >>= 1) m = fmaxf(m, __shfl_xor(m, o, 64));
      float pA = __expf(sA - m);
      float pB = (lane < 36) ? __expf(sB - m) : 0.f;
      float sm = pA + pB;
      #pragma unroll
      for (int o = 32; o > 0; o >>= 1) sm += __shfl_xor(sm, o, 64);
      float inv = RCP(sm);
      scoreW[w][lane] = pA * inv;
      if (lane < 36) scoreW[w][64+lane] = pB * inv;
      __builtin_amdgcn_wave_barrier();
      // ctx[k], k = t, stride 51 dwords (odd -> conflict-free)
      const uint_t* rowp = (const uint_t*)&encBT[t*102];
      float a0 = 0.f, a1 = 0.f;
      #pragma unroll 5
      for (int s2 = 0; s2 < 50; ++s2) {
        uint_t u = rowp[s2];
        float2 sc = *(const float2*)&scoreW[w][2*s2];
        a0 += bflo(u)*sc.x;
        a1 += bfhi(u)*sc.y;
      }
      ctx[t] = a0 + a1;
    }
    __syncthreads();                                   // barrier 2
    // --- E: gates (thread t = gate row), ah from register ---
    if (t < 192) {
      float ai0 = inpb[0]*wx0 + inpb[1]*wx1 + inpb[2]*wx2;
      float ai1 = 0.f;
      #pragma unroll
      for (int kk = 0; kk < 64; ++kk) {
        uint_t wv = wihc[kk];
        float2 c2 = *(const float2*)&ctx[2*kk];        // broadcast
        ai0 += c2.x*bflo(wv);
        ai1 += c2.y*bfhi(wv);
      }
      float ai = ai0 + ai1;
      if (t < 128) gbuf[t] = fsig(ai + ah + brz_r);
      else { gbuf[t] = ai + bni_r; gbuf[64+t] = ah + bnh_r; }  // slots 128..191 / 192..255
    }
    __syncthreads();                                   // barrier 3
    // --- F: combine + prediction (t<64) ---
    if (t < 64) {
      float r = gbuf[t], z = gbuf[64+t];
      float nn = ftanh(gbuf[128+t] + r*gbuf[192+t]);
      float hv = nn + z*(hbuf[t] - nn);
      hbuf[t] = hv;
      float p0 = hv*outWs[t], p1 = hv*outWs[64+t], p2 = hv*outWs[128+t];
      #pragma unroll
      for (int o = 32; o > 0; o >>= 1) {
        p0 += __shfl_xor(p0, o, 64);
        p1 += __shfl_xor(p1, o, 64);
        p2 += __shfl_xor(p2, o, 64);
      }
      if (t < 3) {
        float pv = (t==0) ? p0 : ((t==1) ? p1 : p2);
        pv += outbs[t];
        out[((n>>5)*PRED + st)*96 + (n&31)*3 + t] = pv;
        inpb[t] = pv;
      }
    }
    __syncthreads();                                   // barrier 4
  }
}

extern "C" void kernel_launch(void* const* d_in, const int* in_sizes, int n_in,
                              void* d_out, int out_size, void* d_ws, size_t ws_size,
                              hipStream_t stream)
{
  const float* src   = (const float*)d_in[0];
  const float* WihF  = (const float*)d_in[1];
  const float* WhhF  = (const float*)d_in[2];
  const float* bihF  = (const float*)d_in[3];
  const float* bhhF  = (const float*)d_in[4];
  const float* WihB  = (const float*)d_in[5];
  const float* WhhB  = (const float*)d_in[6];
  const float* bihB  = (const float*)d_in[7];
  const float* bhhB  = (const float*)d_in[8];
  const float* attnW = (const float*)d_in[9];
  const float* attnb = (const float*)d_in[10];
  const float* attnv = (const float*)d_in[11];
  const float* e2dW  = (const float*)d_in[12];
  const float* e2db  = (const float*)d_in[13];
  const float* dWih  = (const float*)d_in[14];
  const float* dWhh  = (const float*)d_in[15];
  const float* dbih  = (const float*)d_in[16];
  const float* dbhh  = (const float*)d_in[17];
  const float* outW  = (const float*)d_in[18];
  const float* outb  = (const float*)d_in[19];

  char* w = (char*)d_ws;
  ushort_t* encO   = (ushort_t*)w;                         // 104,857,600 B
  ushort_t* encWbG = (ushort_t*)(w + 104857600);           //  52,428,800 B
  float*    hlast  = (float*)   (w + 157286400);           //   2,097,152 B
  float*    h0g    = (float*)   (w + 159383552);           //   1,048,576 B
  float* out = (float*)d_out;

  hipLaunchKernelGGL(k_encoder, dim3(512), dim3(256), 0, stream,
                     src, WihF, WhhF, bihF, bhhF, WihB, WhhB, bihB, bhhB, encO, hlast);
  hipLaunchKernelGGL(k_hdec0, dim3(1024), dim3(256), 0, stream, hlast, e2dW, e2db, h0g);
  hipLaunchKernelGGL(k_encwb, dim3(4267), dim3(512), 0, stream, encO, attnW, attnb, encWbG);
  hipLaunchKernelGGL(k_decoder, dim3(4096), dim3(256), 0, stream,
                     src, encO, encWbG, h0g, attnW, attnv, dWih, dWhh, dbih, dbhh, outW, outb, out);
}

// Round 10
// 2127.686 us; speedup vs baseline: 1.9200x; 1.9200x over previous
//
#include <hip/hip_runtime.h>
#include <stdint.h>

#define SLEN 100
#define NSEQ 4096
#define PRED 12

typedef unsigned short ushort_t;
typedef unsigned int uint_t;

#if __has_builtin(__builtin_amdgcn_rcpf)
#define RCP(x) __builtin_amdgcn_rcpf(x)
#else
#define RCP(x) (1.0f/(x))
#endif

__device__ __forceinline__ float bfu(ushort_t u){ return __uint_as_float(((uint_t)u)<<16); }
__device__ __forceinline__ float bflo(uint_t u){ return __uint_as_float(u<<16); }
__device__ __forceinline__ float bfhi(uint_t u){ return __uint_as_float(u & 0xffff0000u); }
__device__ __forceinline__ ushort_t f2bf(float f){
  uint_t u = __float_as_uint(f);
  u += 0x7fffu + ((u>>16)&1u);
  return (ushort_t)(u>>16);
}
__device__ __forceinline__ uint_t pk2(float a, float b){
  return (uint_t)f2bf(a) | ((uint_t)f2bf(b)<<16);
}
__device__ __forceinline__ float fsig(float x){ return RCP(1.f + __expf(-x)); }
__device__ __forceinline__ float ftanh(float x){ float e = __expf(x+x); return 1.f - 2.f*RCP(e+1.f); }
// force v_readlane (uniform broadcast on the VALU pipe, NOT ds_bpermute)
__device__ __forceinline__ float RL(float v, int k){
  return __uint_as_float((uint_t)__builtin_amdgcn_readlane((int)__float_as_uint(v), k));
}

// ---------------- Encoder: bidirectional GRU, ZERO LDS ----------------
// grid 512: blockIdx<256 fwd, >=256 bwd. block=256 (4 waves), wave = 4 seqs.
// Lane j holds Whh row j in 96 packed-bf16 VGPRs; h broadcast by readlane.
// UNCHANGED from round 9 (need its counters once decoder stops dominating).
__global__ __launch_bounds__(256, 2)
void k_encoder(const float* __restrict__ src,
               const float* __restrict__ WihF, const float* __restrict__ WhhF,
               const float* __restrict__ bihF, const float* __restrict__ bhhF,
               const float* __restrict__ WihB, const float* __restrict__ WhhB,
               const float* __restrict__ bihB, const float* __restrict__ bhhB,
               ushort_t* __restrict__ encO, float* __restrict__ hlast)
{
  const int t = threadIdx.x;
  const int dir = blockIdx.x >> 8;
  const int grp = blockIdx.x & 255;
  const float* Wih = dir ? WihB : WihF;
  const float* Whh = dir ? WhhB : WhhF;
  const float* bih = dir ? bihB : bihF;
  const float* bhh = dir ? bhhB : bhhF;

  const int w = t >> 6, lane = t & 63;
  const int n0 = grp*16 + w*4;

  // lane j's weight rows, packed bf16 (96 VGPRs)
  uint_t wrz[64], wn2[32];
  #pragma unroll
  for (int k = 0; k < 64; ++k)
    wrz[k] = pk2(Whh[lane*64 + k], Whh[(64+lane)*64 + k]);
  #pragma unroll
  for (int kk = 0; kk < 32; ++kk)
    wn2[kk] = pk2(Whh[(128+lane)*64 + 2*kk], Whh[(128+lane)*64 + 2*kk+1]);

  float rw[3][3];
  #pragma unroll
  for (int g = 0; g < 3; ++g)
    #pragma unroll
    for (int i = 0; i < 3; ++i)
      rw[g][i] = Wih[(g*64 + lane)*3 + i];
  const float br  = bih[lane]     + bhh[lane];
  const float bz  = bih[64+lane]  + bhh[64+lane];
  const float bni = bih[128+lane];
  const float bnh = bhh[128+lane];

  float h0=0.f, h1=0.f, h2=0.f, h3=0.f;

  // prefetch step-0 x (12 values: 4 seqs x 3 features on lanes 0..11)
  float xv = 0.f;
  {
    const int s0 = dir ? (SLEN-1) : 0;
    if (lane < 12) {
      int q = lane/3, i = lane - q*3, n = n0 + q;
      xv = src[(((n>>5)*SLEN + s0)*96) + (n&31)*3 + i];
    }
  }

  for (int st = 0; st < SLEN; ++st) {
    const int sidx = dir ? (SLEN-1 - st) : st;
    // broadcast current x from lanes 0..11
    const float x00=RL(xv,0),  x01=RL(xv,1),  x02=RL(xv,2);
    const float x10=RL(xv,3),  x11=RL(xv,4),  x12=RL(xv,5);
    const float x20=RL(xv,6),  x21=RL(xv,7),  x22=RL(xv,8);
    const float x30=RL(xv,9),  x31=RL(xv,10), x32=RL(xv,11);
    // issue next step's load; latency hides under the k-loop
    float xnx = 0.f;
    if (st+1 < SLEN) {
      const int sn = dir ? (SLEN-2 - st) : (st+1);
      if (lane < 12) {
        int q = lane/3, i = lane - q*3, n = n0 + q;
        xnx = src[(((n>>5)*SLEN + sn)*96) + (n&31)*3 + i];
      }
    }

    float ar0 = br  + x00*rw[0][0] + x01*rw[0][1] + x02*rw[0][2];
    float az0 = bz  + x00*rw[1][0] + x01*rw[1][1] + x02*rw[1][2];
    float gn0 = bni + x00*rw[2][0] + x01*rw[2][1] + x02*rw[2][2];
    float ar1 = br  + x10*rw[0][0] + x11*rw[0][1] + x12*rw[0][2];
    float az1 = bz  + x10*rw[1][0] + x11*rw[1][1] + x12*rw[1][2];
    float gn1 = bni + x10*rw[2][0] + x11*rw[2][1] + x12*rw[2][2];
    float ar2 = br  + x20*rw[0][0] + x21*rw[0][1] + x22*rw[0][2];
    float az2 = bz  + x20*rw[1][0] + x21*rw[1][1] + x22*rw[1][2];
    float gn2 = bni + x20*rw[2][0] + x21*rw[2][1] + x22*rw[2][2];
    float ar3 = br  + x30*rw[0][0] + x31*rw[0][1] + x32*rw[0][2];
    float az3 = bz  + x30*rw[1][0] + x31*rw[1][1] + x32*rw[1][2];
    float gn3 = bni + x30*rw[2][0] + x31*rw[2][1] + x32*rw[2][2];
    float an0 = bnh, an1 = bnh, an2 = bnh, an3 = bnh;

    #pragma unroll
    for (int k = 0; k < 64; ++k) {
      const float hk0 = RL(h0,k), hk1 = RL(h1,k), hk2 = RL(h2,k), hk3 = RL(h3,k);
      const float wr_ = bflo(wrz[k]), wz_ = bfhi(wrz[k]);
      const float wn_ = (k & 1) ? bfhi(wn2[k>>1]) : bflo(wn2[k>>1]);
      ar0 += hk0*wr_; az0 += hk0*wz_; an0 += hk0*wn_;
      ar1 += hk1*wr_; az1 += hk1*wz_; an1 += hk1*wn_;
      ar2 += hk2*wr_; az2 += hk2*wz_; an2 += hk2*wn_;
      ar3 += hk3*wr_; az3 += hk3*wz_; an3 += hk3*wn_;
    }
    {
      float r = fsig(ar0), z = fsig(az0);
      float nn = ftanh(gn0 + r*an0);
      h0 = nn + z*(h0 - nn);
      encO[((n0+0)*SLEN + sidx)*128 + dir*64 + lane] = f2bf(h0);
    }
    {
      float r = fsig(ar1), z = fsig(az1);
      float nn = ftanh(gn1 + r*an1);
      h1 = nn + z*(h1 - nn);
      encO[((n0+1)*SLEN + sidx)*128 + dir*64 + lane] = f2bf(h1);
    }
    {
      float r = fsig(ar2), z = fsig(az2);
      float nn = ftanh(gn2 + r*an2);
      h2 = nn + z*(h2 - nn);
      encO[((n0+2)*SLEN + sidx)*128 + dir*64 + lane] = f2bf(h2);
    }
    {
      float r = fsig(ar3), z = fsig(az3);
      float nn = ftanh(gn3 + r*an3);
      h3 = nn + z*(h3 - nn);
      encO[((n0+3)*SLEN + sidx)*128 + dir*64 + lane] = f2bf(h3);
    }
    xv = xnx;
  }
  hlast[(dir*NSEQ + n0+0)*64 + lane] = h0;
  hlast[(dir*NSEQ + n0+1)*64 + lane] = h1;
  hlast[(dir*NSEQ + n0+2)*64 + lane] = h2;
  hlast[(dir*NSEQ + n0+3)*64 + lane] = h3;
}

// ---------------- h_dec0 = [hf|hb] @ e2d_W.T + e2d_b ----------------
__global__ __launch_bounds__(256)
void k_hdec0(const float* __restrict__ hlast, const float* __restrict__ e2dW,
             const float* __restrict__ e2db, float* __restrict__ h0g)
{
  const int t = threadIdx.x, w = t>>6, lane = t&63;
  const int n = blockIdx.x*4 + w;
  const float* hf = hlast + n*64;
  const float* hb = hlast + (NSEQ + n)*64;
  float a0 = e2db[lane], a1 = 0.f;
  #pragma unroll 4
  for (int k = 0; k < 64; k += 2) {
    a0 += hf[k]  *e2dW[lane*128 + k]      + hb[k]  *e2dW[lane*128 + 64 + k];
    a1 += hf[k+1]*e2dW[lane*128 + k + 1]  + hb[k+1]*e2dW[lane*128 + 65 + k];
  }
  h0g[n*64 + lane] = a0 + a1;
}

// ---------------- encWb = enc_out @ We.T + attn_b (step-invariant) ----------------
__global__ __launch_bounds__(512)
void k_encwb(const ushort_t* __restrict__ encO, const float* __restrict__ attnW,
             const float* __restrict__ attnb, ushort_t* __restrict__ encWbG)
{
  __shared__ __align__(16) uint_t encL[96*64];   // 96 rows x 128 bf16
  __shared__ __align__(16) float  WeT[128*64];   // [k][j]
  const int t = threadIdx.x;
  const int row0 = blockIdx.x * 96;
  const int nrows = (409600 - row0) < 96 ? (409600 - row0) : 96;
  const uint_t* srcp = (const uint_t*)(encO) + row0*64;
  for (int e = t; e < nrows*64; e += 512) encL[e] = srcp[e];
  for (int e = t; e < 8192; e += 512) {
    int j = e >> 7, k = e & 127;
    WeT[k*64 + j] = attnW[j*192 + 64 + k];
  }
  __syncthreads();
  const int w = t>>6, lane = t&63;
  const float ab = attnb[lane];
  for (int rr = 0; rr < 12; ++rr) {
    int row = w*12 + rr;
    if (row0 + row >= 409600) break;
    float a0 = ab, a1 = 0.f;
    #pragma unroll 8
    for (int k2 = 0; k2 < 64; ++k2) {
      uint_t u = encL[row*64 + k2];
      a0 += bflo(u)*WeT[(2*k2  )*64 + lane];
      a1 += bfhi(u)*WeT[(2*k2+1)*64 + lane];
    }
    encWbG[(row0+row)*64 + lane] = f2bf(a0 + a1);
  }
}

// ---------------- Decoder: 12 fused steps, 4 barriers/step ----------------
// block = 1 seq, 256 thr. Identical structure to round 9 (numerically
// validated), but __launch_bounds__(256,2): the (256,3) cap (~170 VGPR)
// spilled the 128 weight-array VGPRs to scratch -> 2.8GB scratch reads,
// 8.5% VALUBusy, 5x regression. Cap 256 fits arrays+working set (~170).
__global__ __launch_bounds__(256, 2)
void k_decoder(const float* __restrict__ src,
               const ushort_t* __restrict__ encO, const ushort_t* __restrict__ encWbG,
               const float* __restrict__ h0g,
               const float* __restrict__ attnW, const float* __restrict__ attnv,
               const float* __restrict__ dWih, const float* __restrict__ dWhh,
               const float* __restrict__ dbih, const float* __restrict__ dbhh,
               const float* __restrict__ outWg, const float* __restrict__ outbg,
               float* __restrict__ out)
{
  __shared__ __align__(16) ushort_t encBT[128*102]; // enc^T [k][s], pad 102 (odd dwords)
  __shared__ __align__(16) ushort_t encWbL[100*66]; // [s][j], pad 66
  __shared__ __align__(16) float hWw[4][64];        // per-wave hW slices
  __shared__ __align__(16) float scoreW[2][104];    // per-wave score slices (waves 0,1)
  __shared__ __align__(16) float ctx[128];
  __shared__ __align__(16) float gbuf[256];
  __shared__ __align__(16) float hbuf[64];
  __shared__ __align__(16) float vat[64];
  __shared__ __align__(16) float outWs[192];
  __shared__ __align__(16) float outbs[4];
  __shared__ __align__(16) float inpb[4];

  const int t = threadIdx.x;
  const int n = blockIdx.x;
  const int w = t >> 6, lane = t & 63;

  // Register weights:
  uint_t wihc[64];  // t<192: dWih ctx-part row t, packed bf16
  uint_t whh2[32];  // t<192: dWhh row t, packed bf16
  uint_t whp[32];   // all:   attnW hid-part row j=lane, packed bf16
  float  wx0=0.f, wx1=0.f, wx2=0.f;  // t<192: dWih x-part (fp32)
  float  brz_r=0.f, bni_r=0.f, bnh_r=0.f;
  #pragma unroll
  for (int kk = 0; kk < 32; ++kk)
    whp[kk] = pk2(attnW[lane*192 + 2*kk], attnW[lane*192 + 2*kk + 1]);
  if (t < 192) {
    const float* wr = dWih + t*131 + 3;
    #pragma unroll
    for (int kk = 0; kk < 64; ++kk) wihc[kk] = pk2(wr[2*kk], wr[2*kk+1]);
    const float* hr = dWhh + t*64;
    #pragma unroll
    for (int kk = 0; kk < 32; ++kk) whh2[kk] = pk2(hr[2*kk], hr[2*kk+1]);
    wx0 = dWih[t*131 + 0]; wx1 = dWih[t*131 + 1]; wx2 = dWih[t*131 + 2];
    if (t < 128) brz_r = dbih[t] + dbhh[t];
    else { bni_r = dbih[t]; bnh_r = dbhh[t]; }   // t in [128,192): rows 128..191 = n-gate
  }
  // LDS fills
  const ushort_t* eb = encO + n*12800;
  for (int e = t; e < 12800; e += 256) {
    int s = e >> 7, k = e & 127;
    encBT[k*102 + s] = eb[e];
  }
  const ushort_t* ew = encWbG + n*6400;
  for (int e = t; e < 6400; e += 256) {
    int s = e >> 6, j = e & 63;
    encWbL[s*66 + j] = ew[e];
  }
  if (t < 192) outWs[t] = outWg[t];
  if (t < 64) { vat[t] = attnv[t]; hbuf[t] = h0g[n*64+t]; }
  if (t < 4)  outbs[t] = (t < 3) ? outbg[t] : 0.f;
  if (t < 3)  inpb[t] = src[((n>>5)*SLEN + (SLEN-1))*96 + (n&31)*3 + t];
  __syncthreads();

  for (int st = 0; st < PRED; ++st) {
    // --- pre-B (no barrier): per-wave redundant hW; per-thread ah ---
    {
      float hw = 0.f;
      #pragma unroll
      for (int kk = 0; kk < 32; ++kk) {
        float2 h2 = *(const float2*)&hbuf[2*kk];   // broadcast
        uint_t u = whp[kk];
        hw += h2.x*bflo(u) + h2.y*bfhi(u);
      }
      hWw[w][lane] = hw;   // wave-private
    }
    float ah = 0.f;
    if (t < 192) {
      #pragma unroll
      for (int kk = 0; kk < 32; ++kk) {
        float2 h2 = *(const float2*)&hbuf[2*kk];   // broadcast
        uint_t u = whh2[kk];
        ah += h2.x*bflo(u) + h2.y*bfhi(u);
      }
    }
    __builtin_amdgcn_wave_barrier();
    // --- B: score partials, (jh = t>>7, s = t&127); reads own wave's hW slice ---
    {
      const int s = t & 127, jh = t >> 7;
      if (s < 100) {
        const ushort_t* erow = &encWbL[s*66 + jh*32];
        float p = 0.f;
        #pragma unroll
        for (int j4 = 0; j4 < 8; ++j4) {
          float4 hw4 = *(const float4*)&hWw[w][jh*32 + j4*4];
          uint_t u0 = *(const uint_t*)&erow[j4*4];
          uint_t u1 = *(const uint_t*)&erow[j4*4 + 2];
          float4 vv = *(const float4*)&vat[jh*32 + j4*4];
          p += ftanh(hw4.x + bflo(u0))*vv.x;
          p += ftanh(hw4.y + bfhi(u0))*vv.y;
          p += ftanh(hw4.z + bflo(u1))*vv.z;
          p += ftanh(hw4.w + bfhi(u1))*vv.w;
        }
        gbuf[t] = p;
      }
    }
    __syncthreads();                                   // barrier 1
    // --- C+D fused: waves 0,1 redundant softmax -> own slice -> ctx ---
    if (t < 128) {
      float sA = gbuf[lane] + gbuf[128+lane];
      float sB = (lane < 36) ? (gbuf[64+lane] + gbuf[192+lane]) : -1e30f;
      float m = fmaxf(sA, sB);
      #pragma unroll
      for (int o = 32; o > 0; o >>= 1) m = fmaxf(m, __shfl_xor(m, o, 64));
      float pA = __expf(sA - m);
      float pB = (lane < 36) ? __expf(sB - m) : 0.f;
      float sm = pA + pB;
      #pragma unroll
      for (int o = 32; o > 0; o >>= 1) sm += __shfl_xor(sm, o, 64);
      float inv = RCP(sm);
      scoreW[w][lane] = pA * inv;
      if (lane < 36) scoreW[w][64+lane] = pB * inv;
      __builtin_amdgcn_wave_barrier();
      // ctx[k], k = t, stride 51 dwords (odd -> conflict-free)
      const uint_t* rowp = (const uint_t*)&encBT[t*102];
      float a0 = 0.f, a1 = 0.f;
      #pragma unroll 5
      for (int s2 = 0; s2 < 50; ++s2) {
        uint_t u = rowp[s2];
        float2 sc = *(const float2*)&scoreW[w][2*s2];
        a0 += bflo(u)*sc.x;
        a1 += bfhi(u)*sc.y;
      }
      ctx[t] = a0 + a1;
    }
    __syncthreads();                                   // barrier 2
    // --- E: gates (thread t = gate row), ah from register ---
    if (t < 192) {
      float ai0 = inpb[0]*wx0 + inpb[1]*wx1 + inpb[2]*wx2;
      float ai1 = 0.f;
      #pragma unroll
      for (int kk = 0; kk < 64; ++kk) {
        uint_t wv = wihc[kk];
        float2 c2 = *(const float2*)&ctx[2*kk];        // broadcast
        ai0 += c2.x*bflo(wv);
        ai1 += c2.y*bfhi(wv);
      }
      float ai = ai0 + ai1;
      if (t < 128) gbuf[t] = fsig(ai + ah + brz_r);
      else { gbuf[t] = ai + bni_r; gbuf[64+t] = ah + bnh_r; }  // slots 128..191 / 192..255
    }
    __syncthreads();                                   // barrier 3
    // --- F: combine + prediction (t<64) ---
    if (t < 64) {
      float r = gbuf[t], z = gbuf[64+t];
      float nn = ftanh(gbuf[128+t] + r*gbuf[192+t]);
      float hv = nn + z*(hbuf[t] - nn);
      hbuf[t] = hv;
      float p0 = hv*outWs[t], p1 = hv*outWs[64+t], p2 = hv*outWs[128+t];
      #pragma unroll
      for (int o = 32; o > 0; o >>= 1) {
        p0 += __shfl_xor(p0, o, 64);
        p1 += __shfl_xor(p1, o, 64);
        p2 += __shfl_xor(p2, o, 64);
      }
      if (t < 3) {
        float pv = (t==0) ? p0 : ((t==1) ? p1 : p2);
        pv += outbs[t];
        out[((n>>5)*PRED + st)*96 + (n&31)*3 + t] = pv;
        inpb[t] = pv;
      }
    }
    __syncthreads();                                   // barrier 4
  }
}

extern "C" void kernel_launch(void* const* d_in, const int* in_sizes, int n_in,
                              void* d_out, int out_size, void* d_ws, size_t ws_size,
                              hipStream_t stream)
{
  const float* src   = (const float*)d_in[0];
  const float* WihF  = (const float*)d_in[1];
  const float* WhhF  = (const float*)d_in[2];
  const float* bihF  = (const float*)d_in[3];
  const float* bhhF  = (const float*)d_in[4];
  const float* WihB  = (const float*)d_in[5];
  const float* WhhB  = (const float*)d_in[6];
  const float* bihB  = (const float*)d_in[7];
  const float* bhhB  = (const float*)d_in[8];
  const float* attnW = (const float*)d_in[9];
  const float* attnb = (const float*)d_in[10];
  const float* attnv = (const float*)d_in[11];
  const float* e2dW  = (const float*)d_in[12];
  const float* e2db  = (const float*)d_in[13];
  const float* dWih  = (const float*)d_in[14];
  const float* dWhh  = (const float*)d_in[15];
  const float* dbih  = (const float*)d_in[16];
  const float* dbhh  = (const float*)d_in[17];
  const float* outW  = (const float*)d_in[18];
  const float* outb  = (const float*)d_in[19];

  char* w = (char*)d_ws;
  ushort_t* encO   = (ushort_t*)w;                         // 104,857,600 B
  ushort_t* encWbG = (ushort_t*)(w + 104857600);           //  52,428,800 B
  float*    hlast  = (float*)   (w + 157286400);           //   2,097,152 B
  float*    h0g    = (float*)   (w + 159383552);           //   1,048,576 B
  float* out = (float*)d_out;

  hipLaunchKernelGGL(k_encoder, dim3(512), dim3(256), 0, stream,
                     src, WihF, WhhF, bihF, bhhF, WihB, WhhB, bihB, bhhB, encO, hlast);
  hipLaunchKernelGGL(k_hdec0, dim3(1024), dim3(256), 0, stream, hlast, e2dW, e2db, h0g);
  hipLaunchKernelGGL(k_encwb, dim3(4267), dim3(512), 0, stream, encO, attnW, attnb, encWbG);
  hipLaunchKernelGGL(k_decoder, dim3(4096), dim3(256), 0, stream,
                     src, encO, encWbG, h0g, attnW, attnv, dWih, dWhh, dbih, dbhh, outW, outb, out);
}

// Round 11
// 2123.591 us; speedup vs baseline: 1.9237x; 1.0019x over previous
//
#include <hip/hip_runtime.h>
#include <stdint.h>

#define SLEN 100
#define NSEQ 4096
#define PRED 12

typedef unsigned short ushort_t;
typedef unsigned int uint_t;

#if __has_builtin(__builtin_amdgcn_rcpf)
#define RCP(x) __builtin_amdgcn_rcpf(x)
#else
#define RCP(x) (1.0f/(x))
#endif

__device__ __forceinline__ float bfu(ushort_t u){ return __uint_as_float(((uint_t)u)<<16); }
__device__ __forceinline__ float bflo(uint_t u){ return __uint_as_float(u<<16); }
__device__ __forceinline__ float bfhi(uint_t u){ return __uint_as_float(u & 0xffff0000u); }
__device__ __forceinline__ ushort_t f2bf(float f){
  uint_t u = __float_as_uint(f);
  u += 0x7fffu + ((u>>16)&1u);
  return (ushort_t)(u>>16);
}
__device__ __forceinline__ uint_t pk2(float a, float b){
  return (uint_t)f2bf(a) | ((uint_t)f2bf(b)<<16);
}
__device__ __forceinline__ float fsig(float x){ return RCP(1.f + __expf(-x)); }
__device__ __forceinline__ float ftanh(float x){ float e = __expf(x+x); return 1.f - 2.f*RCP(e+1.f); }
// force v_readlane (uniform broadcast on the VALU pipe, NOT ds_bpermute)
__device__ __forceinline__ float RL(float v, int k){
  return __uint_as_float((uint_t)__builtin_amdgcn_readlane((int)__float_as_uint(v), k));
}

// ---------------- Encoder: bidirectional GRU, ZERO LDS ----------------
// grid 512: blockIdx<256 fwd, >=256 bwd. block=256 (4 waves), wave = 4 seqs.
// Lane j holds Whh row j in 96 packed-bf16 VGPRs; h broadcast by readlane.
// waves_per_eu(2,2): pin VGPR budget at 256/wave. Round-10 evidence: with
// only a min bound, the allocator targeted 4 waves/SIMD (128 VGPR) and
// spilled the weight arrays to scratch (decoder WRITE_SIZE 285MB).
__global__ __attribute__((amdgpu_waves_per_eu(2, 2))) __launch_bounds__(256)
void k_encoder(const float* __restrict__ src,
               const float* __restrict__ WihF, const float* __restrict__ WhhF,
               const float* __restrict__ bihF, const float* __restrict__ bhhF,
               const float* __restrict__ WihB, const float* __restrict__ WhhB,
               const float* __restrict__ bihB, const float* __restrict__ bhhB,
               ushort_t* __restrict__ encO, float* __restrict__ hlast)
{
  const int t = threadIdx.x;
  const int dir = blockIdx.x >> 8;
  const int grp = blockIdx.x & 255;
  const float* Wih = dir ? WihB : WihF;
  const float* Whh = dir ? WhhB : WhhF;
  const float* bih = dir ? bihB : bihF;
  const float* bhh = dir ? bhhB : bhhF;

  const int w = t >> 6, lane = t & 63;
  const int n0 = grp*16 + w*4;

  // lane j's weight rows, packed bf16 (96 VGPRs)
  uint_t wrz[64], wn2[32];
  #pragma unroll
  for (int k = 0; k < 64; ++k)
    wrz[k] = pk2(Whh[lane*64 + k], Whh[(64+lane)*64 + k]);
  #pragma unroll
  for (int kk = 0; kk < 32; ++kk)
    wn2[kk] = pk2(Whh[(128+lane)*64 + 2*kk], Whh[(128+lane)*64 + 2*kk+1]);

  float rw[3][3];
  #pragma unroll
  for (int g = 0; g < 3; ++g)
    #pragma unroll
    for (int i = 0; i < 3; ++i)
      rw[g][i] = Wih[(g*64 + lane)*3 + i];
  const float br  = bih[lane]     + bhh[lane];
  const float bz  = bih[64+lane]  + bhh[64+lane];
  const float bni = bih[128+lane];
  const float bnh = bhh[128+lane];

  float h0=0.f, h1=0.f, h2=0.f, h3=0.f;

  // prefetch step-0 x (12 values: 4 seqs x 3 features on lanes 0..11)
  float xv = 0.f;
  {
    const int s0 = dir ? (SLEN-1) : 0;
    if (lane < 12) {
      int q = lane/3, i = lane - q*3, n = n0 + q;
      xv = src[(((n>>5)*SLEN + s0)*96) + (n&31)*3 + i];
    }
  }

  for (int st = 0; st < SLEN; ++st) {
    const int sidx = dir ? (SLEN-1 - st) : st;
    // broadcast current x from lanes 0..11
    const float x00=RL(xv,0),  x01=RL(xv,1),  x02=RL(xv,2);
    const float x10=RL(xv,3),  x11=RL(xv,4),  x12=RL(xv,5);
    const float x20=RL(xv,6),  x21=RL(xv,7),  x22=RL(xv,8);
    const float x30=RL(xv,9),  x31=RL(xv,10), x32=RL(xv,11);
    // issue next step's load; latency hides under the k-loop
    float xnx = 0.f;
    if (st+1 < SLEN) {
      const int sn = dir ? (SLEN-2 - st) : (st+1);
      if (lane < 12) {
        int q = lane/3, i = lane - q*3, n = n0 + q;
        xnx = src[(((n>>5)*SLEN + sn)*96) + (n&31)*3 + i];
      }
    }

    float ar0 = br  + x00*rw[0][0] + x01*rw[0][1] + x02*rw[0][2];
    float az0 = bz  + x00*rw[1][0] + x01*rw[1][1] + x02*rw[1][2];
    float gn0 = bni + x00*rw[2][0] + x01*rw[2][1] + x02*rw[2][2];
    float ar1 = br  + x10*rw[0][0] + x11*rw[0][1] + x12*rw[0][2];
    float az1 = bz  + x10*rw[1][0] + x11*rw[1][1] + x12*rw[1][2];
    float gn1 = bni + x10*rw[2][0] + x11*rw[2][1] + x12*rw[2][2];
    float ar2 = br  + x20*rw[0][0] + x21*rw[0][1] + x22*rw[0][2];
    float az2 = bz  + x20*rw[1][0] + x21*rw[1][1] + x22*rw[1][2];
    float gn2 = bni + x20*rw[2][0] + x21*rw[2][1] + x22*rw[2][2];
    float ar3 = br  + x30*rw[0][0] + x31*rw[0][1] + x32*rw[0][2];
    float az3 = bz  + x30*rw[1][0] + x31*rw[1][1] + x32*rw[1][2];
    float gn3 = bni + x30*rw[2][0] + x31*rw[2][1] + x32*rw[2][2];
    float an0 = bnh, an1 = bnh, an2 = bnh, an3 = bnh;

    #pragma unroll
    for (int k = 0; k < 64; ++k) {
      const float hk0 = RL(h0,k), hk1 = RL(h1,k), hk2 = RL(h2,k), hk3 = RL(h3,k);
      const float wr_ = bflo(wrz[k]), wz_ = bfhi(wrz[k]);
      const float wn_ = (k & 1) ? bfhi(wn2[k>>1]) : bflo(wn2[k>>1]);
      ar0 += hk0*wr_; az0 += hk0*wz_; an0 += hk0*wn_;
      ar1 += hk1*wr_; az1 += hk1*wz_; an1 += hk1*wn_;
      ar2 += hk2*wr_; az2 += hk2*wz_; an2 += hk2*wn_;
      ar3 += hk3*wr_; az3 += hk3*wz_; an3 += hk3*wn_;
    }
    {
      float r = fsig(ar0), z = fsig(az0);
      float nn = ftanh(gn0 + r*an0);
      h0 = nn + z*(h0 - nn);
      encO[((n0+0)*SLEN + sidx)*128 + dir*64 + lane] = f2bf(h0);
    }
    {
      float r = fsig(ar1), z = fsig(az1);
      float nn = ftanh(gn1 + r*an1);
      h1 = nn + z*(h1 - nn);
      encO[((n0+1)*SLEN + sidx)*128 + dir*64 + lane] = f2bf(h1);
    }
    {
      float r = fsig(ar2), z = fsig(az2);
      float nn = ftanh(gn2 + r*an2);
      h2 = nn + z*(h2 - nn);
      encO[((n0+2)*SLEN + sidx)*128 + dir*64 + lane] = f2bf(h2);
    }
    {
      float r = fsig(ar3), z = fsig(az3);
      float nn = ftanh(gn3 + r*an3);
      h3 = nn + z*(h3 - nn);
      encO[((n0+3)*SLEN + sidx)*128 + dir*64 + lane] = f2bf(h3);
    }
    xv = xnx;
  }
  hlast[(dir*NSEQ + n0+0)*64 + lane] = h0;
  hlast[(dir*NSEQ + n0+1)*64 + lane] = h1;
  hlast[(dir*NSEQ + n0+2)*64 + lane] = h2;
  hlast[(dir*NSEQ + n0+3)*64 + lane] = h3;
}

// ---------------- h_dec0 = [hf|hb] @ e2d_W.T + e2d_b ----------------
__global__ __launch_bounds__(256)
void k_hdec0(const float* __restrict__ hlast, const float* __restrict__ e2dW,
             const float* __restrict__ e2db, float* __restrict__ h0g)
{
  const int t = threadIdx.x, w = t>>6, lane = t&63;
  const int n = blockIdx.x*4 + w;
  const float* hf = hlast + n*64;
  const float* hb = hlast + (NSEQ + n)*64;
  float a0 = e2db[lane], a1 = 0.f;
  #pragma unroll 4
  for (int k = 0; k < 64; k += 2) {
    a0 += hf[k]  *e2dW[lane*128 + k]      + hb[k]  *e2dW[lane*128 + 64 + k];
    a1 += hf[k+1]*e2dW[lane*128 + k + 1]  + hb[k+1]*e2dW[lane*128 + 65 + k];
  }
  h0g[n*64 + lane] = a0 + a1;
}

// ---------------- encWb = enc_out @ We.T + attn_b (step-invariant) ----------------
__global__ __launch_bounds__(512)
void k_encwb(const ushort_t* __restrict__ encO, const float* __restrict__ attnW,
             const float* __restrict__ attnb, ushort_t* __restrict__ encWbG)
{
  __shared__ __align__(16) uint_t encL[96*64];   // 96 rows x 128 bf16
  __shared__ __align__(16) float  WeT[128*64];   // [k][j]
  const int t = threadIdx.x;
  const int row0 = blockIdx.x * 96;
  const int nrows = (409600 - row0) < 96 ? (409600 - row0) : 96;
  const uint_t* srcp = (const uint_t*)(encO) + row0*64;
  for (int e = t; e < nrows*64; e += 512) encL[e] = srcp[e];
  for (int e = t; e < 8192; e += 512) {
    int j = e >> 7, k = e & 127;
    WeT[k*64 + j] = attnW[j*192 + 64 + k];
  }
  __syncthreads();
  const int w = t>>6, lane = t&63;
  const float ab = attnb[lane];
  for (int rr = 0; rr < 12; ++rr) {
    int row = w*12 + rr;
    if (row0 + row >= 409600) break;
    float a0 = ab, a1 = 0.f;
    #pragma unroll 8
    for (int k2 = 0; k2 < 64; ++k2) {
      uint_t u = encL[row*64 + k2];
      a0 += bflo(u)*WeT[(2*k2  )*64 + lane];
      a1 += bfhi(u)*WeT[(2*k2+1)*64 + lane];
    }
    encWbG[(row0+row)*64 + lane] = f2bf(a0 + a1);
  }
}

// ---------------- Decoder: 12 fused steps, 4 barriers/step ----------------
// block = 1 seq, 256 thr. Structure identical to rounds 9/10 (numerically
// validated). waves_per_eu(2,2) pins the VGPR budget at 256: round 10 showed
// the allocator otherwise targets 4 waves/SIMD (128 VGPR) and spills the
// 128-VGPR weight arrays (WRITE_SIZE 285MB of scratch stores, VALUBusy 21%).
__global__ __attribute__((amdgpu_waves_per_eu(2, 2))) __launch_bounds__(256)
void k_decoder(const float* __restrict__ src,
               const ushort_t* __restrict__ encO, const ushort_t* __restrict__ encWbG,
               const float* __restrict__ h0g,
               const float* __restrict__ attnW, const float* __restrict__ attnv,
               const float* __restrict__ dWih, const float* __restrict__ dWhh,
               const float* __restrict__ dbih, const float* __restrict__ dbhh,
               const float* __restrict__ outWg, const float* __restrict__ outbg,
               float* __restrict__ out)
{
  __shared__ __align__(16) ushort_t encBT[128*102]; // enc^T [k][s], pad 102 (odd dwords)
  __shared__ __align__(16) ushort_t encWbL[100*66]; // [s][j], pad 66
  __shared__ __align__(16) float hWw[4][64];        // per-wave hW slices
  __shared__ __align__(16) float scoreW[2][104];    // per-wave score slices (waves 0,1)
  __shared__ __align__(16) float ctx[128];
  __shared__ __align__(16) float gbuf[256];
  __shared__ __align__(16) float hbuf[64];
  __shared__ __align__(16) float vat[64];
  __shared__ __align__(16) float outWs[192];
  __shared__ __align__(16) float outbs[4];
  __shared__ __align__(16) float inpb[4];

  const int t = threadIdx.x;
  const int n = blockIdx.x;
  const int w = t >> 6, lane = t & 63;

  // Register weights:
  uint_t wihc[64];  // t<192: dWih ctx-part row t, packed bf16
  uint_t whh2[32];  // t<192: dWhh row t, packed bf16
  uint_t whp[32];   // all:   attnW hid-part row j=lane, packed bf16
  float  wx0=0.f, wx1=0.f, wx2=0.f;  // t<192: dWih x-part (fp32)
  float  brz_r=0.f, bni_r=0.f, bnh_r=0.f;
  #pragma unroll
  for (int kk = 0; kk < 32; ++kk)
    whp[kk] = pk2(attnW[lane*192 + 2*kk], attnW[lane*192 + 2*kk + 1]);
  if (t < 192) {
    const float* wr = dWih + t*131 + 3;
    #pragma unroll
    for (int kk = 0; kk < 64; ++kk) wihc[kk] = pk2(wr[2*kk], wr[2*kk+1]);
    const float* hr = dWhh + t*64;
    #pragma unroll
    for (int kk = 0; kk < 32; ++kk) whh2[kk] = pk2(hr[2*kk], hr[2*kk+1]);
    wx0 = dWih[t*131 + 0]; wx1 = dWih[t*131 + 1]; wx2 = dWih[t*131 + 2];
    if (t < 128) brz_r = dbih[t] + dbhh[t];
    else { bni_r = dbih[t]; bnh_r = dbhh[t]; }   // t in [128,192): rows 128..191 = n-gate
  }
  // LDS fills
  const ushort_t* eb = encO + n*12800;
  for (int e = t; e < 12800; e += 256) {
    int s = e >> 7, k = e & 127;
    encBT[k*102 + s] = eb[e];
  }
  const ushort_t* ew = encWbG + n*6400;
  for (int e = t; e < 6400; e += 256) {
    int s = e >> 6, j = e & 63;
    encWbL[s*66 + j] = ew[e];
  }
  if (t < 192) outWs[t] = outWg[t];
  if (t < 64) { vat[t] = attnv[t]; hbuf[t] = h0g[n*64+t]; }
  if (t < 4)  outbs[t] = (t < 3) ? outbg[t] : 0.f;
  if (t < 3)  inpb[t] = src[((n>>5)*SLEN + (SLEN-1))*96 + (n&31)*3 + t];
  __syncthreads();

  for (int st = 0; st < PRED; ++st) {
    // --- pre-B (no barrier): per-wave redundant hW; per-thread ah ---
    {
      float hw = 0.f;
      #pragma unroll
      for (int kk = 0; kk < 32; ++kk) {
        float2 h2 = *(const float2*)&hbuf[2*kk];   // broadcast
        uint_t u = whp[kk];
        hw += h2.x*bflo(u) + h2.y*bfhi(u);
      }
      hWw[w][lane] = hw;   // wave-private
    }
    float ah = 0.f;
    if (t < 192) {
      #pragma unroll
      for (int kk = 0; kk < 32; ++kk) {
        float2 h2 = *(const float2*)&hbuf[2*kk];   // broadcast
        uint_t u = whh2[kk];
        ah += h2.x*bflo(u) + h2.y*bfhi(u);
      }
    }
    __builtin_amdgcn_wave_barrier();
    // --- B: score partials, (jh = t>>7, s = t&127); reads own wave's hW slice ---
    {
      const int s = t & 127, jh = t >> 7;
      if (s < 100) {
        const ushort_t* erow = &encWbL[s*66 + jh*32];
        float p = 0.f;
        #pragma unroll
        for (int j4 = 0; j4 < 8; ++j4) {
          float4 hw4 = *(const float4*)&hWw[w][jh*32 + j4*4];
          uint_t u0 = *(const uint_t*)&erow[j4*4];
          uint_t u1 = *(const uint_t*)&erow[j4*4 + 2];
          float4 vv = *(const float4*)&vat[jh*32 + j4*4];
          p += ftanh(hw4.x + bflo(u0))*vv.x;
          p += ftanh(hw4.y + bfhi(u0))*vv.y;
          p += ftanh(hw4.z + bflo(u1))*vv.z;
          p += ftanh(hw4.w + bfhi(u1))*vv.w;
        }
        gbuf[t] = p;
      }
    }
    __syncthreads();                                   // barrier 1
    // --- C+D fused: waves 0,1 redundant softmax -> own slice -> ctx ---
    if (t < 128) {
      float sA = gbuf[lane] + gbuf[128+lane];
      float sB = (lane < 36) ? (gbuf[64+lane] + gbuf[192+lane]) : -1e30f;
      float m = fmaxf(sA, sB);
      #pragma unroll
      for (int o = 32; o > 0; o >>= 1) m = fmaxf(m, __shfl_xor(m, o, 64));
      float pA = __expf(sA - m);
      float pB = (lane < 36) ? __expf(sB - m) : 0.f;
      float sm = pA + pB;
      #pragma unroll
      for (int o = 32; o > 0; o >>= 1) sm += __shfl_xor(sm, o, 64);
      float inv = RCP(sm);
      scoreW[w][lane] = pA * inv;
      if (lane < 36) scoreW[w][64+lane] = pB * inv;
      __builtin_amdgcn_wave_barrier();
      // ctx[k], k = t, stride 51 dwords (odd -> conflict-free)
      const uint_t* rowp = (const uint_t*)&encBT[t*102];
      float a0 = 0.f, a1 = 0.f;
      #pragma unroll 5
      for (int s2 = 0; s2 < 50; ++s2) {
        uint_t u = rowp[s2];
        float2 sc = *(const float2*)&scoreW[w][2*s2];
        a0 += bflo(u)*sc.x;
        a1 += bfhi(u)*sc.y;
      }
      ctx[t] = a0 + a1;
    }
    __syncthreads();                                   // barrier 2
    // --- E: gates (thread t = gate row), ah from register ---
    if (t < 192) {
      float ai0 = inpb[0]*wx0 + inpb[1]*wx1 + inpb[2]*wx2;
      float ai1 = 0.f;
      #pragma unroll
      for (int kk = 0; kk < 64; ++kk) {
        uint_t wv = wihc[kk];
        float2 c2 = *(const float2*)&ctx[2*kk];        // broadcast
        ai0 += c2.x*bflo(wv);
        ai1 += c2.y*bfhi(wv);
      }
      float ai = ai0 + ai1;
      if (t < 128) gbuf[t] = fsig(ai + ah + brz_r);
      else { gbuf[t] = ai + bni_r; gbuf[64+t] = ah + bnh_r; }  // slots 128..191 / 192..255
    }
    __syncthreads();                                   // barrier 3
    // --- F: combine + prediction (t<64) ---
    if (t < 64) {
      float r = gbuf[t], z = gbuf[64+t];
      float nn = ftanh(gbuf[128+t] + r*gbuf[192+t]);
      float hv = nn + z*(hbuf[t] - nn);
      hbuf[t] = hv;
      float p0 = hv*outWs[t], p1 = hv*outWs[64+t], p2 = hv*outWs[128+t];
      #pragma unroll
      for (int o = 32; o > 0; o >>= 1) {
        p0 += __shfl_xor(p0, o, 64);
        p1 += __shfl_xor(p1, o, 64);
        p2 += __shfl_xor(p2, o, 64);
      }
      if (t < 3) {
        float pv = (t==0) ? p0 : ((t==1) ? p1 : p2);
        pv += outbs[t];
        out[((n>>5)*PRED + st)*96 + (n&31)*3 + t] = pv;
        inpb[t] = pv;
      }
    }
    __syncthreads();                                   // barrier 4
  }
}

extern "C" void kernel_launch(void* const* d_in, const int* in_sizes, int n_in,
                              void* d_out, int out_size, void* d_ws, size_t ws_size,
                              hipStream_t stream)
{
  const float* src   = (const float*)d_in[0];
  const float* WihF  = (const float*)d_in[1];
  const float* WhhF  = (const float*)d_in[2];
  const float* bihF  = (const float*)d_in[3];
  const float* bhhF  = (const float*)d_in[4];
  const float* WihB  = (const float*)d_in[5];
  const float* WhhB  = (const float*)d_in[6];
  const float* bihB  = (const float*)d_in[7];
  const float* bhhB  = (const float*)d_in[8];
  const float* attnW = (const float*)d_in[9];
  const float* attnb = (const float*)d_in[10];
  const float* attnv = (const float*)d_in[11];
  const float* e2dW  = (const float*)d_in[12];
  const float* e2db  = (const float*)d_in[13];
  const float* dWih  = (const float*)d_in[14];
  const float* dWhh  = (const float*)d_in[15];
  const float* dbih  = (const float*)d_in[16];
  const float* dbhh  = (const float*)d_in[17];
  const float* outW  = (const float*)d_in[18];
  const float* outb  = (const float*)d_in[19];

  char* w = (char*)d_ws;
  ushort_t* encO   = (ushort_t*)w;                         // 104,857,600 B
  ushort_t* encWbG = (ushort_t*)(w + 104857600);           //  52,428,800 B
  float*    hlast  = (float*)   (w + 157286400);           //   2,097,152 B
  float*    h0g    = (float*)   (w + 159383552);           //   1,048,576 B
  float* out = (float*)d_out;

  hipLaunchKernelGGL(k_encoder, dim3(512), dim3(256), 0, stream,
                     src, WihF, WhhF, bihF, bhhF, WihB, WhhB, bihB, bhhB, encO, hlast);
  hipLaunchKernelGGL(k_hdec0, dim3(1024), dim3(256), 0, stream, hlast, e2dW, e2db, h0g);
  hipLaunchKernelGGL(k_encwb, dim3(4267), dim3(512), 0, stream, encO, attnW, attnb, encWbG);
  hipLaunchKernelGGL(k_decoder, dim3(4096), dim3(256), 0, stream,
                     src, encO, encWbG, h0g, attnW, attnv, dWih, dWhh, dbih, dbhh, outW, outb, out);
}